// Round 8
// baseline (500.529 us; speedup 1.0000x reference)
//
#include <hip/hip_runtime.h>

// ---------------------------------------------------------------------------
// Fused attention: qp = q@Wq+bq ; kp = k@Wk+bk ; vp = v@Wv+bv
// S = qp kp^T / 16 ; A = softmax(S) ; A = where(threefry_mask, A/0.8, 0)
// out = A vp.   B=4, L=4096, D=256, DV=64.  fp32 in/out, bf16 MFMA internally.
//
// R7: async K-staging (prefetch next tile to regs, ds_write after barrier —
// removes global latency from the barrier-critical path), V tile into regs
// covered by threefry, KSPLIT=4 (grid 1024 = exactly 4 blocks/CU, single
// generation per XCD, K/V sets L2-resident), partO halved.
// ---------------------------------------------------------------------------

typedef short s16x8 __attribute__((ext_vector_type(8)));   // 8 bf16 (4 VGPR)
typedef short s16x4 __attribute__((ext_vector_type(4)));
typedef float f32x4 __attribute__((ext_vector_type(4)));

#define L    4096
#define DM   256
#define DV   64
#define MTOT 16384            // B*L rows
#define KSPLIT 4
#define KBLK 64               // keys per tile
#define NIT  (L / KSPLIT / KBLK)   // 16
#define CEXP 0.09016844005556021f  // log2(e)/16

__device__ __forceinline__ short f2bf(float f) {           // RNE fp32->bf16
  unsigned u = __builtin_bit_cast(unsigned, f);
  u += 0x7FFFu + ((u >> 16) & 1u);
  return (short)(u >> 16);
}
__device__ __forceinline__ float bf2f(short s) {
  unsigned u = ((unsigned)(unsigned short)s) << 16;
  return __builtin_bit_cast(float, u);
}
__device__ __forceinline__ unsigned rotl32c(unsigned x, int r) {
  return (x << r) | (x >> (32 - r));
}

// JAX partitionable threefry2x32, key=(0,42), counter=(0,ctr). Returns
// x0^x1; keep iff bits < 0.8*2^32 (bit-exact, verified R1).
__device__ __forceinline__ unsigned tf_bits(unsigned ctr) {
  unsigned x0 = 0u;
  unsigned x1 = ctr + 42u;
#define TFR(r) { x0 += x1; x1 = rotl32c(x1, r); x1 ^= x0; }
  TFR(13) TFR(15) TFR(26) TFR(6)
  x0 += 42u;          x1 += 0x1BD11BF1u;                   // ks2=0x1BD11BDA^42, +1
  TFR(17) TFR(29) TFR(16) TFR(24)
  x0 += 0x1BD11BF0u;  x1 += 2u;
  TFR(13) TFR(15) TFR(26) TFR(6)
  /* x0 += 0 */       x1 += 45u;                           // 42 + 3
  TFR(17) TFR(29) TFR(16) TFR(24)
  x0 += 42u;          x1 += 0x1BD11BF4u;                   // ks2 + 4
  TFR(13) TFR(15) TFR(26) TFR(6)
  x0 += 0x1BD11BF0u;  x1 += 5u;
#undef TFR
  return x0 ^ x1;
}

// ---------------------------------------------------------------------------
// Prep: W -> W^T bf16; Wq/bq pre-scaled by log2e/16.
// ---------------------------------------------------------------------------
__global__ __launch_bounds__(256) void prep_kernel(
    const float* __restrict__ Wq, const float* __restrict__ bq,
    const float* __restrict__ Wk, const float* __restrict__ Wv,
    short* __restrict__ wqT, short* __restrict__ wkT,
    short* __restrict__ wvT, float* __restrict__ bqs) {
  const int idx = blockIdx.x * 256 + threadIdx.x;
  if (idx < 65536) {                       // Wq 256x256 -> wqT[n*256+k], scaled
    const int n = idx >> 8, k = idx & 255;
    wqT[idx] = f2bf(Wq[k * 256 + n] * CEXP);
  }
  if (idx < 8192) {                        // Wk 32x256 -> wkT[n*32+k]
    const int n = idx >> 5, k = idx & 31;
    wkT[idx] = f2bf(Wk[k * 256 + n]);
  }
  if (idx < 16384) {                       // Wv 256x64 -> wvT[n*256+k]
    const int n = idx >> 8, k = idx & 255;
    wvT[idx] = f2bf(Wv[k * 64 + n]);
  }
  if (idx < 256) bqs[idx] = bq[idx] * CEXP;
}

// ---------------------------------------------------------------------------
// Shared projection body: acc[nt] = A[rows 16/wave] @ W (W^T bf16 given).
// MFMA 16x16x32 frags: A/B lane (l&15)=m/n, k=(l>>4)*8+j ; C row=(l>>4)*4+j,
// col=l&15.
// ---------------------------------------------------------------------------
template <int K>
__device__ __forceinline__ void proj_acc(
    const float* __restrict__ A, const short* __restrict__ WT,
    int arow, int ncol0, int l15, int l4, f32x4 acc[4]) {
#pragma unroll
  for (int kc = 0; kc < K / 32; ++kc) {
    const f32x4* ap = (const f32x4*)(A + (size_t)arow * K + kc * 32 + l4 * 8);
    f32x4 a0 = ap[0], a1 = ap[1];
    s16x8 af;
#pragma unroll
    for (int j = 0; j < 4; ++j) { af[j] = f2bf(a0[j]); af[4 + j] = f2bf(a1[j]); }
#pragma unroll
    for (int nt = 0; nt < 4; ++nt) {
      const s16x8 bf = *(const s16x8*)(WT + (size_t)(ncol0 + nt * 16 + l15) * K + kc * 32 + l4 * 8);
      acc[nt] = __builtin_amdgcn_mfma_f32_16x16x32_bf16(af, bf, acc[nt], 0, 0, 0);
    }
  }
}

// ---------------------------------------------------------------------------
// Fused projections, one launch:
//  blocks [0,1024):   qp[row][n] ;  rb=part&255, nc0=(part>>8)*64
//  blocks [1024,2048): kp[row][n]
//  blocks [2048,2304): vpT[b*64+dv][key] via LDS transpose (64 rows x 64 dv)
// ---------------------------------------------------------------------------
__global__ __launch_bounds__(256) void proj_all_kernel(
    const float* __restrict__ q, const float* __restrict__ k,
    const float* __restrict__ v, const short* __restrict__ wqT,
    const short* __restrict__ wkT, const short* __restrict__ wvT,
    const float* __restrict__ bqs, const float* __restrict__ bk,
    const float* __restrict__ bv, short* __restrict__ qp,
    short* __restrict__ kpb, short* __restrict__ vpT) {
  __shared__ __align__(16) short tbuf[64 * 64];  // v transpose tile, 8 KB
  const int part = blockIdx.x;
  const int tid = threadIdx.x;
  const int lane = tid & 63, wv = tid >> 6;
  const int l15 = lane & 15, l4 = lane >> 4;
  f32x4 acc[4];
#pragma unroll
  for (int i = 0; i < 4; ++i) acc[i] = (f32x4){0.f, 0.f, 0.f, 0.f};

  if (part < 2048) {
    const bool isq = part < 1024;
    const int p = isq ? part : part - 1024;
    const int rowbase = (p & 255) * 64 + wv * 16;
    const int nc0 = (p >> 8) * 64;
    if (isq) proj_acc<256>(q, wqT, rowbase + l15, nc0, l15, l4, acc);
    else     proj_acc<32>(k, wkT, rowbase + l15, nc0, l15, l4, acc);
    const float* bias = isq ? bqs : bk;
    short* out = isq ? qp : kpb;
#pragma unroll
    for (int nt = 0; nt < 4; ++nt) {
      const float bb = bias[nc0 + nt * 16 + l15];
#pragma unroll
      for (int j = 0; j < 4; ++j)
        out[(size_t)(rowbase + l4 * 4 + j) * DM + nc0 + nt * 16 + l15] =
            f2bf(acc[nt][j] + bb);
    }
  } else {
    // ---- v-projection with transposed output ----
    const int p = part - 2048;                 // 0..255
    const int rowbase0 = p * 64;               // global key-row base
    const int rowbase = rowbase0 + wv * 16;
    proj_acc<256>(v, wvT, rowbase + l15, 0, l15, l4, acc);
#pragma unroll
    for (int nt = 0; nt < 4; ++nt) {
      const float bb = bv[nt * 16 + l15];
#pragma unroll
      for (int j = 0; j < 4; ++j)             // tbuf[dv][key_local]
        tbuf[(nt * 16 + l15) * 64 + (wv * 16 + l4 * 4 + j)] = f2bf(acc[nt][j] + bb);
    }
    __syncthreads();
    const int b = rowbase0 >> 12, key0 = rowbase0 & 4095;
#pragma unroll
    for (int it = 0; it < 2; ++it) {          // 512 8-key chunks / 256 thr
      const int c = it * 256 + tid;
      const int dv = c & 63, k8 = (c >> 6) * 8;
      *(s16x8*)(vpT + (size_t)(b * 64 + dv) * L + key0 + k8) =
          *(const s16x8*)(tbuf + dv * 64 + k8);
    }
  }
}

// ---------------------------------------------------------------------------
// Fused flash attention + exact-threefry dropout, split-K, XCD-swizzled.
// 1-D grid 1024 (exactly 4 blocks/CU, one generation).
// swz=(wg&7)*128+(wg>>3): XCD r owns z=r>>1 and a b-pair -> K set 1MB,
// V set 256KB per XCD, all-resident reuse.
// Per iter: prefetch NEXT K tile to regs (latency under QK+threefry),
// ds_write after barrier; V tile to regs after threefry (latency under
// barrier-wait + ds_writes + pbuf reads). 2 barriers/iter.
// ---------------------------------------------------------------------------
__global__ __launch_bounds__(256, 4) void attn_kernel(
    const short* __restrict__ qp, const short* __restrict__ kp,
    const short* __restrict__ vpT, short* __restrict__ partO,
    float* __restrict__ partZ) {
  __shared__ __align__(16) short kbuf[KBLK * 256];   // 32 KB
  __shared__ __align__(16) short pbuf[4][16 * KBLK]; // 8 KB
  const int tid = threadIdx.x;
  const int lane = tid & 63, wv = tid >> 6;
  const int l15 = lane & 15, l4 = lane >> 4;
  const int wg = blockIdx.x;
  const int swz = (wg & 7) * 128 + (wg >> 3);
  const int qt = swz & 63, g = swz >> 6;         // g in [0,16)
  const int b = g & 3, z = g >> 2;
  const int qrow0 = b * L + qt * 64 + wv * 16;   // global row in [MTOT]

  s16x8 qf[8];                                   // Q frags (Wq pre-scaled)
#pragma unroll
  for (int kc = 0; kc < 8; ++kc)
    qf[kc] = *(const s16x8*)(qp + (size_t)(qrow0 + l15) * DM + kc * 32 + l4 * 8);

  f32x4 accO[4];
#pragma unroll
  for (int i = 0; i < 4; ++i) accO[i] = (f32x4){0.f, 0.f, 0.f, 0.f};
  float zpart[4] = {0.f, 0.f, 0.f, 0.f};
  const unsigned qglob = (unsigned)qrow0;

  // K staging geometry: thread owns 8 chunks; row = it*8+rowA, off = offA.
  const int rowA = tid >> 5, offA = (tid & 31) * 8;
  const int eBase = (rowA * 256 + offA) ^ ((rowA & 7) << 3);  // swizzle const
  const short* ksrc = kp + (size_t)b * L * DM;
  const int kb0 = z * (L / KSPLIT);

  s16x8 kreg[8];
  {  // prologue: fill kbuf with tile 0
#pragma unroll
    for (int it = 0; it < 8; ++it)
      kreg[it] = *(const s16x8*)(ksrc + (size_t)(kb0 + it * 8 + rowA) * DM + offA);
#pragma unroll
    for (int it = 0; it < 8; ++it)
      *(s16x8*)(kbuf + it * 2048 + eBase) = kreg[it];
  }
  __syncthreads();

  for (int i = 0; i < NIT; ++i) {
    const int kbase = kb0 + i * KBLK;
    const int knext = kbase + ((i + 1 < NIT) ? KBLK : 0);
    // ---- prefetch next K tile into regs (consumed after barrier1) ----
#pragma unroll
    for (int it = 0; it < 8; ++it)
      kreg[it] = *(const s16x8*)(ksrc + (size_t)(knext + it * 8 + rowA) * DM + offA);

    // ---- QK^T: 4 key-tiles x 8 k-chunks ----
    f32x4 sf[4];
#pragma unroll
    for (int kt = 0; kt < 4; ++kt) sf[kt] = (f32x4){0.f, 0.f, 0.f, 0.f};
#pragma unroll
    for (int kc = 0; kc < 8; ++kc) {
#pragma unroll
      for (int kt = 0; kt < 4; ++kt) {
        const int row = kt * 16 + l15;
        const int e = (row * 256 + kc * 32 + l4 * 8) ^ ((row & 7) << 3);
        const s16x8 kf = *(const s16x8*)(kbuf + e);
        sf[kt] = __builtin_amdgcn_mfma_f32_16x16x32_bf16(qf[kc], kf, sf[kt], 0, 0, 0);
      }
    }

    // ---- exp + fused threefry dropout + Z + masked P into pbuf ----
#pragma unroll
    for (int kt = 0; kt < 4; ++kt) {
#pragma unroll
      for (int j = 0; j < 4; ++j) {
        const float e = exp2f(sf[kt][j]);
        zpart[j] += e;
        const unsigned idx = ((qglob + (unsigned)(l4 * 4 + j)) << 12) +
                             (unsigned)(kbase + kt * 16 + l15);
        const float pd = (tf_bits(idx) < 3435974144u) ? e : 0.0f;
        const int row = l4 * 4 + j, col = kt * 16 + l15;
        pbuf[wv][(row * KBLK + col) ^ ((row & 7) << 3)] = f2bf(pd);
      }
    }

    // ---- V tile into regs (latency under barrier + ds_writes) ----
    s16x8 vreg[8];
#pragma unroll
    for (int ks = 0; ks < 2; ++ks)
#pragma unroll
      for (int nt = 0; nt < 4; ++nt)
        vreg[ks * 4 + nt] = *(const s16x8*)(
            vpT + (size_t)(b * 64 + nt * 16 + l15) * L + kbase + ks * 32 + l4 * 8);

    __syncthreads();   // all waves done with kbuf QK reads
    // ---- write prefetched K tile (waits kreg vmcnt, V stays in flight) ----
#pragma unroll
    for (int it = 0; it < 8; ++it)
      *(s16x8*)(kbuf + it * 2048 + eBase) = kreg[it];

    // ---- PV: P[16x64] @ V[64x64] (pbuf per-wave, lgkm-ordered) ----
#pragma unroll
    for (int ks = 0; ks < 2; ++ks) {
      const int pe = (l15 * KBLK + ks * 32 + l4 * 8) ^ ((l15 & 7) << 3);
      const s16x8 pa = *(const s16x8*)(&pbuf[wv][0] + pe);
#pragma unroll
      for (int nt = 0; nt < 4; ++nt)
        accO[nt] = __builtin_amdgcn_mfma_f32_16x16x32_bf16(pa, vreg[ks * 4 + nt],
                                                           accO[nt], 0, 0, 0);
    }
    __syncthreads();   // kbuf holds tile i+1 for every wave
  }

  // ---- epilogue: Z reduce + coalesced partO via LDS bounce ----
#pragma unroll
  for (int j = 0; j < 4; ++j) {
    float zf = zpart[j];
    zf += __shfl_xor(zf, 1);
    zf += __shfl_xor(zf, 2);
    zf += __shfl_xor(zf, 4);
    zf += __shfl_xor(zf, 8);
    if (l15 == 0) partZ[(size_t)z * MTOT + qrow0 + l4 * 4 + j] = zf;
  }
  __syncthreads();                       // all waves done with kbuf
  float* fb = (float*)kbuf + wv * 1024;  // 16x64 f32 per wave
#pragma unroll
  for (int nt = 0; nt < 4; ++nt)
#pragma unroll
    for (int j = 0; j < 4; ++j)
      fb[(l4 * 4 + j) * 64 + nt * 16 + l15] = accO[nt][j];
  // same-wave read (lgkmcnt-ordered)
  const int r = lane >> 2, c0 = (lane & 3) * 16;
  s16x8 o0, o1;
#pragma unroll
  for (int m = 0; m < 8; ++m) o0[m] = f2bf(fb[r * 64 + c0 + m]);
#pragma unroll
  for (int m = 0; m < 8; ++m) o1[m] = f2bf(fb[r * 64 + c0 + 8 + m]);
  short* od = partO + ((size_t)z * MTOT + qrow0 + r) * DV + c0;
  *(s16x8*)(od) = o0;
  *(s16x8*)(od + 8) = o1;
}

// ---------------------------------------------------------------------------
// Combine: out[row][dv] = sum_z O / (0.8 * sum_z Z[row]).  4 f32 per thread.
// ---------------------------------------------------------------------------
__global__ __launch_bounds__(256) void combine_kernel(
    const short* __restrict__ partO, const float* __restrict__ partZ,
    float* __restrict__ out) {
  const int i = blockIdx.x * 256 + threadIdx.x;  // groups of 4 f32
  const int row = i >> 4, col0 = (i & 15) * 4;
  f32x4 acc = (f32x4){0.f, 0.f, 0.f, 0.f};
  float zf = 0.f;
#pragma unroll
  for (int z = 0; z < KSPLIT; ++z) {
    const s16x4 p = *(const s16x4*)(partO + (((size_t)z * MTOT + row) << 6) + col0);
#pragma unroll
    for (int m = 0; m < 4; ++m) acc[m] += bf2f(p[m]);
    zf += partZ[(size_t)z * MTOT + row];
  }
  const float inv = 1.0f / (0.8f * zf);
  *(f32x4*)(out + (size_t)i * 4) = acc * inv;
}

// ---------------------------------------------------------------------------
extern "C" void kernel_launch(void* const* d_in, const int* in_sizes, int n_in,
                              void* d_out, int out_size, void* d_ws, size_t ws_size,
                              hipStream_t stream) {
  const float* q  = (const float*)d_in[0];
  const float* k  = (const float*)d_in[1];
  const float* v  = (const float*)d_in[2];
  const float* Wq = (const float*)d_in[3];
  const float* bq = (const float*)d_in[4];
  const float* Wk = (const float*)d_in[5];
  const float* bk = (const float*)d_in[6];
  const float* Wv = (const float*)d_in[7];
  const float* bv = (const float*)d_in[8];
  float* out = (float*)d_out;

  // ws: qp 8.4 | kp 8.4 | vpT 2.1 | partO(bf16) 8.4 | partZ 0.26 | W bufs ~0.2
  short* qp  = (short*)d_ws;
  short* kpb = qp + (size_t)MTOT * DM;
  short* vpT = kpb + (size_t)MTOT * DM;
  short* partO = vpT + (size_t)MTOT * DV;
  float* partZ = (float*)(partO + (size_t)KSPLIT * MTOT * DV);
  short* wqT = (short*)(partZ + (size_t)KSPLIT * MTOT);
  short* wkT = wqT + 256 * 256;
  short* wvT = wkT + 32 * 256;
  float* bqs = (float*)(wvT + 64 * 256);

  prep_kernel<<<256, 256, 0, stream>>>(Wq, bq, Wk, Wv, wqT, wkT, wvT, bqs);
  proj_all_kernel<<<2304, 256, 0, stream>>>(q, k, v, wqT, wkT, wvT,
                                            bqs, bk, bv, qp, kpb, vpT);
  attn_kernel<<<1024, 256, 0, stream>>>(qp, kpb, vpT, partO, partZ);
  combine_kernel<<<MTOT * DV / 1024, 256, 0, stream>>>(partO, partZ, out);
}

// Round 9
// 323.525 us; speedup vs baseline: 1.5471x; 1.5471x over previous
//
#include <hip/hip_runtime.h>

// ---------------------------------------------------------------------------
// Fused attention: qp = q@Wq+bq ; kp = k@Wk+bk ; vp = v@Wv+bv
// S = qp kp^T / 16 ; A = softmax(S) ; A = where(threefry_mask, A/0.8, 0)
// out = A vp.   B=4, L=4096, D=256, DV=64.  fp32 in/out, bf16 MFMA internally.
//
// R8: plain __launch_bounds__(256) (R2-R7's min-waves arg made the compiler
// minimize to 40-64 VGPRs and SPILL — the 100-265MB "mystery" WRITE_SIZE),
// nontemporal loads/stores for stream-once data (Q/partO/proj-A/qp) so K/V
// slices stay L2-resident, raw v_exp_f32, last-iter prefetch guard, setprio
// around MFMA clusters. Structure otherwise = R7.
// ---------------------------------------------------------------------------

typedef short s16x8 __attribute__((ext_vector_type(8)));   // 8 bf16 (4 VGPR)
typedef short s16x4 __attribute__((ext_vector_type(4)));
typedef float f32x4 __attribute__((ext_vector_type(4)));

#define L    4096
#define DM   256
#define DV   64
#define MTOT 16384            // B*L rows
#define KSPLIT 4
#define KBLK 64               // keys per tile
#define NIT  (L / KSPLIT / KBLK)   // 16
#define CEXP 0.09016844005556021f  // log2(e)/16

__device__ __forceinline__ short f2bf(float f) {           // RNE fp32->bf16
  unsigned u = __builtin_bit_cast(unsigned, f);
  u += 0x7FFFu + ((u >> 16) & 1u);
  return (short)(u >> 16);
}
__device__ __forceinline__ float bf2f(short s) {
  unsigned u = ((unsigned)(unsigned short)s) << 16;
  return __builtin_bit_cast(float, u);
}
__device__ __forceinline__ unsigned rotl32c(unsigned x, int r) {
  return (x << r) | (x >> (32 - r));
}

// JAX partitionable threefry2x32, key=(0,42), counter=(0,ctr). Returns
// x0^x1; keep iff bits < 0.8*2^32 (bit-exact, verified R1).
__device__ __forceinline__ unsigned tf_bits(unsigned ctr) {
  unsigned x0 = 0u;
  unsigned x1 = ctr + 42u;
#define TFR(r) { x0 += x1; x1 = rotl32c(x1, r); x1 ^= x0; }
  TFR(13) TFR(15) TFR(26) TFR(6)
  x0 += 42u;          x1 += 0x1BD11BF1u;                   // ks2=0x1BD11BDA^42, +1
  TFR(17) TFR(29) TFR(16) TFR(24)
  x0 += 0x1BD11BF0u;  x1 += 2u;
  TFR(13) TFR(15) TFR(26) TFR(6)
  /* x0 += 0 */       x1 += 45u;                           // 42 + 3
  TFR(17) TFR(29) TFR(16) TFR(24)
  x0 += 42u;          x1 += 0x1BD11BF4u;                   // ks2 + 4
  TFR(13) TFR(15) TFR(26) TFR(6)
  x0 += 0x1BD11BF0u;  x1 += 5u;
#undef TFR
  return x0 ^ x1;
}

// ---------------------------------------------------------------------------
// Prep: W -> W^T bf16; Wq/bq pre-scaled by log2e/16.
// ---------------------------------------------------------------------------
__global__ __launch_bounds__(256) void prep_kernel(
    const float* __restrict__ Wq, const float* __restrict__ bq,
    const float* __restrict__ Wk, const float* __restrict__ Wv,
    short* __restrict__ wqT, short* __restrict__ wkT,
    short* __restrict__ wvT, float* __restrict__ bqs) {
  const int idx = blockIdx.x * 256 + threadIdx.x;
  if (idx < 65536) {                       // Wq 256x256 -> wqT[n*256+k], scaled
    const int n = idx >> 8, k = idx & 255;
    wqT[idx] = f2bf(Wq[k * 256 + n] * CEXP);
  }
  if (idx < 8192) {                        // Wk 32x256 -> wkT[n*32+k]
    const int n = idx >> 5, k = idx & 31;
    wkT[idx] = f2bf(Wk[k * 256 + n]);
  }
  if (idx < 16384) {                       // Wv 256x64 -> wvT[n*256+k]
    const int n = idx >> 8, k = idx & 255;
    wvT[idx] = f2bf(Wv[k * 64 + n]);
  }
  if (idx < 256) bqs[idx] = bq[idx] * CEXP;
}

// ---------------------------------------------------------------------------
// Shared projection body: acc[nt] = A[rows 16/wave] @ W (W^T bf16 given).
// A loads nontemporal (stream-once). MFMA 16x16x32 frags: A/B lane (l&15)=m/n,
// k=(l>>4)*8+j ; C row=(l>>4)*4+j, col=l&15.
// ---------------------------------------------------------------------------
template <int K>
__device__ __forceinline__ void proj_acc(
    const float* __restrict__ A, const short* __restrict__ WT,
    int arow, int ncol0, int l15, int l4, f32x4 acc[4]) {
#pragma unroll
  for (int kc = 0; kc < K / 32; ++kc) {
    const f32x4* ap = (const f32x4*)(A + (size_t)arow * K + kc * 32 + l4 * 8);
    f32x4 a0 = __builtin_nontemporal_load(ap);
    f32x4 a1 = __builtin_nontemporal_load(ap + 1);
    s16x8 af;
#pragma unroll
    for (int j = 0; j < 4; ++j) { af[j] = f2bf(a0[j]); af[4 + j] = f2bf(a1[j]); }
#pragma unroll
    for (int nt = 0; nt < 4; ++nt) {
      const s16x8 bf = *(const s16x8*)(WT + (size_t)(ncol0 + nt * 16 + l15) * K + kc * 32 + l4 * 8);
      acc[nt] = __builtin_amdgcn_mfma_f32_16x16x32_bf16(af, bf, acc[nt], 0, 0, 0);
    }
  }
}

// ---------------------------------------------------------------------------
// Fused projections, one launch:
//  blocks [0,1024):   qp[row][n] ;  rb=part&255, nc0=(part>>8)*64
//  blocks [1024,2048): kp[row][n]
//  blocks [2048,2304): vpT[b*64+dv][key] via LDS transpose (64 rows x 64 dv)
// ---------------------------------------------------------------------------
__global__ __launch_bounds__(256) void proj_all_kernel(
    const float* __restrict__ q, const float* __restrict__ k,
    const float* __restrict__ v, const short* __restrict__ wqT,
    const short* __restrict__ wkT, const short* __restrict__ wvT,
    const float* __restrict__ bqs, const float* __restrict__ bk,
    const float* __restrict__ bv, short* __restrict__ qp,
    short* __restrict__ kpb, short* __restrict__ vpT) {
  __shared__ __align__(16) short tbuf[64 * 64];  // v transpose tile, 8 KB
  const int part = blockIdx.x;
  const int tid = threadIdx.x;
  const int lane = tid & 63, wv = tid >> 6;
  const int l15 = lane & 15, l4 = lane >> 4;
  f32x4 acc[4];
#pragma unroll
  for (int i = 0; i < 4; ++i) acc[i] = (f32x4){0.f, 0.f, 0.f, 0.f};

  if (part < 2048) {
    const bool isq = part < 1024;
    const int p = isq ? part : part - 1024;
    const int rowbase = (p & 255) * 64 + wv * 16;
    const int nc0 = (p >> 8) * 64;
    if (isq) proj_acc<256>(q, wqT, rowbase + l15, nc0, l15, l4, acc);
    else     proj_acc<32>(k, wkT, rowbase + l15, nc0, l15, l4, acc);
    const float* bias = isq ? bqs : bk;
    short* out = isq ? qp : kpb;
#pragma unroll
    for (int nt = 0; nt < 4; ++nt) {
      const float bb = bias[nc0 + nt * 16 + l15];
#pragma unroll
      for (int j = 0; j < 4; ++j)
        out[(size_t)(rowbase + l4 * 4 + j) * DM + nc0 + nt * 16 + l15] =
            f2bf(acc[nt][j] + bb);
    }
  } else {
    // ---- v-projection with transposed output ----
    const int p = part - 2048;                 // 0..255
    const int rowbase0 = p * 64;               // global key-row base
    const int rowbase = rowbase0 + wv * 16;
    proj_acc<256>(v, wvT, rowbase + l15, 0, l15, l4, acc);
#pragma unroll
    for (int nt = 0; nt < 4; ++nt) {
      const float bb = bv[nt * 16 + l15];
#pragma unroll
      for (int j = 0; j < 4; ++j)             // tbuf[dv][key_local]
        tbuf[(nt * 16 + l15) * 64 + (wv * 16 + l4 * 4 + j)] = f2bf(acc[nt][j] + bb);
    }
    __syncthreads();
    const int b = rowbase0 >> 12, key0 = rowbase0 & 4095;
#pragma unroll
    for (int it = 0; it < 2; ++it) {          // 512 8-key chunks / 256 thr
      const int c = it * 256 + tid;
      const int dv = c & 63, k8 = (c >> 6) * 8;
      *(s16x8*)(vpT + (size_t)(b * 64 + dv) * L + key0 + k8) =
          *(const s16x8*)(tbuf + dv * 64 + k8);
    }
  }
}

// ---------------------------------------------------------------------------
// Fused flash attention + exact-threefry dropout, split-K, XCD-swizzled.
// 1-D grid 1024 (4 blocks/CU, one generation). swz=(wg&7)*128+(wg>>3):
// XCD r owns 2 (b,z) groups -> K set 1MB, V set 256KB per XCD (L2-resident;
// Q/partO are nontemporal so they don't evict it).
// Per iter: prefetch NEXT K tile to regs (latency under QK+threefry),
// ds_write after barrier; V to regs after threefry. 2 barriers/iter.
// ---------------------------------------------------------------------------
__global__ __launch_bounds__(256) void attn_kernel(
    const short* __restrict__ qp, const short* __restrict__ kp,
    const short* __restrict__ vpT, short* __restrict__ partO,
    float* __restrict__ partZ) {
  __shared__ __align__(16) short kbuf[KBLK * 256];   // 32 KB
  __shared__ __align__(16) short pbuf[4][16 * KBLK]; // 8 KB
  const int tid = threadIdx.x;
  const int lane = tid & 63, wv = tid >> 6;
  const int l15 = lane & 15, l4 = lane >> 4;
  const int wg = blockIdx.x;
  const int swz = (wg & 7) * 128 + (wg >> 3);
  const int qt = swz & 63, g = swz >> 6;         // g in [0,16)
  const int b = g & 3, z = g >> 2;
  const int qrow0 = b * L + qt * 64 + wv * 16;   // global row in [MTOT]

  s16x8 qf[8];                                   // Q frags (Wq pre-scaled), nt
#pragma unroll
  for (int kc = 0; kc < 8; ++kc)
    qf[kc] = __builtin_nontemporal_load(
        (const s16x8*)(qp + (size_t)(qrow0 + l15) * DM + kc * 32 + l4 * 8));

  f32x4 accO[4];
#pragma unroll
  for (int i = 0; i < 4; ++i) accO[i] = (f32x4){0.f, 0.f, 0.f, 0.f};
  float zpart[4] = {0.f, 0.f, 0.f, 0.f};
  const unsigned qglob = (unsigned)qrow0;

  // K staging geometry: thread owns 8 chunks; row = it*8+rowA, off = offA.
  const int rowA = tid >> 5, offA = (tid & 31) * 8;
  const int eBase = (rowA * 256 + offA) ^ ((rowA & 7) << 3);  // swizzle const
  const short* ksrc = kp + (size_t)b * L * DM;
  const int kb0 = z * (L / KSPLIT);

  s16x8 kreg[8];
  {  // prologue: fill kbuf with tile 0
#pragma unroll
    for (int it = 0; it < 8; ++it)
      kreg[it] = *(const s16x8*)(ksrc + (size_t)(kb0 + it * 8 + rowA) * DM + offA);
#pragma unroll
    for (int it = 0; it < 8; ++it)
      *(s16x8*)(kbuf + it * 2048 + eBase) = kreg[it];
  }
  __syncthreads();

  for (int i = 0; i < NIT; ++i) {
    const int kbase = kb0 + i * KBLK;
    const bool pf = (i + 1 < NIT);
    // ---- prefetch next K tile into regs (consumed after barrier1) ----
    if (pf) {
#pragma unroll
      for (int it = 0; it < 8; ++it)
        kreg[it] = *(const s16x8*)(ksrc + (size_t)(kbase + KBLK + it * 8 + rowA) * DM + offA);
    }

    // ---- QK^T: 4 key-tiles x 8 k-chunks ----
    f32x4 sf[4];
#pragma unroll
    for (int kt = 0; kt < 4; ++kt) sf[kt] = (f32x4){0.f, 0.f, 0.f, 0.f};
    __builtin_amdgcn_s_setprio(1);
#pragma unroll
    for (int kc = 0; kc < 8; ++kc) {
#pragma unroll
      for (int kt = 0; kt < 4; ++kt) {
        const int row = kt * 16 + l15;
        const int e = (row * 256 + kc * 32 + l4 * 8) ^ ((row & 7) << 3);
        const s16x8 kf = *(const s16x8*)(kbuf + e);
        sf[kt] = __builtin_amdgcn_mfma_f32_16x16x32_bf16(qf[kc], kf, sf[kt], 0, 0, 0);
      }
    }
    __builtin_amdgcn_s_setprio(0);

    // ---- exp + fused threefry dropout + Z + masked P into pbuf ----
#pragma unroll
    for (int kt = 0; kt < 4; ++kt) {
#pragma unroll
      for (int j = 0; j < 4; ++j) {
        const float e = __builtin_amdgcn_exp2f(sf[kt][j]);
        zpart[j] += e;
        const unsigned idx = ((qglob + (unsigned)(l4 * 4 + j)) << 12) +
                             (unsigned)(kbase + kt * 16 + l15);
        const float pd = (tf_bits(idx) < 3435974144u) ? e : 0.0f;
        const int row = l4 * 4 + j, col = kt * 16 + l15;
        pbuf[wv][(row * KBLK + col) ^ ((row & 7) << 3)] = f2bf(pd);
      }
    }

    // ---- V tile into regs (latency under barrier + ds_writes) ----
    s16x8 vreg[8];
#pragma unroll
    for (int ks = 0; ks < 2; ++ks)
#pragma unroll
      for (int nt = 0; nt < 4; ++nt)
        vreg[ks * 4 + nt] = *(const s16x8*)(
            vpT + (size_t)(b * 64 + nt * 16 + l15) * L + kbase + ks * 32 + l4 * 8);

    __syncthreads();   // all waves done with kbuf QK reads
    // ---- write prefetched K tile (waits kreg vmcnt, V stays in flight) ----
    if (pf) {
#pragma unroll
      for (int it = 0; it < 8; ++it)
        *(s16x8*)(kbuf + it * 2048 + eBase) = kreg[it];
    }

    // ---- PV: P[16x64] @ V[64x64] (pbuf per-wave, lgkm-ordered) ----
    __builtin_amdgcn_s_setprio(1);
#pragma unroll
    for (int ks = 0; ks < 2; ++ks) {
      const int pe = (l15 * KBLK + ks * 32 + l4 * 8) ^ ((l15 & 7) << 3);
      const s16x8 pa = *(const s16x8*)(&pbuf[wv][0] + pe);
#pragma unroll
      for (int nt = 0; nt < 4; ++nt)
        accO[nt] = __builtin_amdgcn_mfma_f32_16x16x32_bf16(pa, vreg[ks * 4 + nt],
                                                           accO[nt], 0, 0, 0);
    }
    __builtin_amdgcn_s_setprio(0);
    __syncthreads();   // kbuf holds tile i+1 for every wave
  }

  // ---- epilogue: Z reduce + coalesced partO via LDS bounce ----
#pragma unroll
  for (int j = 0; j < 4; ++j) {
    float zf = zpart[j];
    zf += __shfl_xor(zf, 1);
    zf += __shfl_xor(zf, 2);
    zf += __shfl_xor(zf, 4);
    zf += __shfl_xor(zf, 8);
    if (l15 == 0) partZ[(size_t)z * MTOT + qrow0 + l4 * 4 + j] = zf;
  }
  __syncthreads();                       // all waves done with kbuf
  float* fb = (float*)kbuf + wv * 1024;  // 16x64 f32 per wave
#pragma unroll
  for (int nt = 0; nt < 4; ++nt)
#pragma unroll
    for (int j = 0; j < 4; ++j)
      fb[(l4 * 4 + j) * 64 + nt * 16 + l15] = accO[nt][j];
  // same-wave read (lgkmcnt-ordered)
  const int r = lane >> 2, c0 = (lane & 3) * 16;
  s16x8 o0, o1;
#pragma unroll
  for (int m = 0; m < 8; ++m) o0[m] = f2bf(fb[r * 64 + c0 + m]);
#pragma unroll
  for (int m = 0; m < 8; ++m) o1[m] = f2bf(fb[r * 64 + c0 + 8 + m]);
  short* od = partO + ((size_t)z * MTOT + qrow0 + r) * DV + c0;
  __builtin_nontemporal_store(o0, (s16x8*)od);
  __builtin_nontemporal_store(o1, (s16x8*)(od + 8));
}

// ---------------------------------------------------------------------------
// Combine: out[row][dv] = sum_z O / (0.8 * sum_z Z[row]).  4 f32 per thread.
// ---------------------------------------------------------------------------
__global__ __launch_bounds__(256) void combine_kernel(
    const short* __restrict__ partO, const float* __restrict__ partZ,
    float* __restrict__ out) {
  const int i = blockIdx.x * 256 + threadIdx.x;  // groups of 4 f32
  const int row = i >> 4, col0 = (i & 15) * 4;
  f32x4 acc = (f32x4){0.f, 0.f, 0.f, 0.f};
  float zf = 0.f;
#pragma unroll
  for (int z = 0; z < KSPLIT; ++z) {
    const s16x4 p = __builtin_nontemporal_load(
        (const s16x4*)(partO + (((size_t)z * MTOT + row) << 6) + col0));
#pragma unroll
    for (int m = 0; m < 4; ++m) acc[m] += bf2f(p[m]);
    zf += partZ[(size_t)z * MTOT + row];
  }
  const float inv = 1.0f / (0.8f * zf);
  f32x4 r = acc * inv;
  __builtin_nontemporal_store(r, (f32x4*)(out + (size_t)i * 4));
}

// ---------------------------------------------------------------------------
extern "C" void kernel_launch(void* const* d_in, const int* in_sizes, int n_in,
                              void* d_out, int out_size, void* d_ws, size_t ws_size,
                              hipStream_t stream) {
  const float* q  = (const float*)d_in[0];
  const float* k  = (const float*)d_in[1];
  const float* v  = (const float*)d_in[2];
  const float* Wq = (const float*)d_in[3];
  const float* bq = (const float*)d_in[4];
  const float* Wk = (const float*)d_in[5];
  const float* bk = (const float*)d_in[6];
  const float* Wv = (const float*)d_in[7];
  const float* bv = (const float*)d_in[8];
  float* out = (float*)d_out;

  // ws: qp 8.4 | kp 8.4 | vpT 2.1 | partO(bf16) 8.4 | partZ 0.26 | W bufs ~0.2
  short* qp  = (short*)d_ws;
  short* kpb = qp + (size_t)MTOT * DM;
  short* vpT = kpb + (size_t)MTOT * DM;
  short* partO = vpT + (size_t)MTOT * DV;
  float* partZ = (float*)(partO + (size_t)KSPLIT * MTOT * DV);
  short* wqT = (short*)(partZ + (size_t)KSPLIT * MTOT);
  short* wkT = wqT + 256 * 256;
  short* wvT = wkT + 32 * 256;
  float* bqs = (float*)(wvT + 64 * 256);

  prep_kernel<<<256, 256, 0, stream>>>(Wq, bq, Wk, Wv, wqT, wkT, wvT, bqs);
  proj_all_kernel<<<2304, 256, 0, stream>>>(q, k, v, wqT, wkT, wvT,
                                            bqs, bk, bv, qp, kpb, vpT);
  attn_kernel<<<1024, 256, 0, stream>>>(qp, kpb, vpT, partO, partZ);
  combine_kernel<<<MTOT * DV / 1024, 256, 0, stream>>>(partO, partZ, out);
}